// Round 10
// baseline (184.082 us; speedup 1.0000x reference)
//
#include <hip/hip_runtime.h>
#include <hip/hip_bf16.h>
#include <stdint.h>

// N=4096, IN=512, OUT=64, H=8. Inputs (fp32): x, adj(int32), W, a1, a2. Output fp32[N, H*OUT].
// ws: bitsT 2MB @0 | WhhT 4MB @2M | f1 @6M | f2 @6M+128K |
//     xh 4MB @6.5M | xl 4MB @10.5M | WTh 512K @14.5M | WTl 512K @15M

constexpr int N_ = 4096, IN_ = 512, OUT_ = 64, H_ = 8;
constexpr float ALPHA_ = 0.2f;

typedef __attribute__((ext_vector_type(8))) short short8;
typedef __attribute__((ext_vector_type(4))) float f32x4;

__device__ __forceinline__ uint32_t rne_pack2(float a, float b, float& ra, float& rb) {
    uint32_t ua = __float_as_uint(a); ua += 0x7fffu + ((ua >> 16) & 1u); ua >>= 16;
    uint32_t ub = __float_as_uint(b); ub += 0x7fffu + ((ub >> 16) & 1u); ub >>= 16;
    ra = __uint_as_float(ua << 16);
    rb = __uint_as_float(ub << 16);
    return ua | (ub << 16);
}

// ---------- fused preprocessing: pack_adj (blocks 0..4095) | split_x (4096..5119)
// | split_wT (5120..5183). FROZEN (R6).
__global__ __launch_bounds__(256) void preprocess(const int* __restrict__ adj,
                                                  unsigned long long* __restrict__ bitsT,
                                                  const float* __restrict__ x,
                                                  uint16_t* __restrict__ xh,
                                                  uint16_t* __restrict__ xl,
                                                  const float* __restrict__ W,
                                                  uint16_t* __restrict__ WTh,
                                                  uint16_t* __restrict__ WTl) {
    __shared__ float T[64 * 68];
    const int b = blockIdx.x;
    if (b < 4096) {
        // ---- pack_adj ----
        size_t base = (size_t)b * 256 + threadIdx.x;
        const size_t stride = (size_t)4096 * 256;
#pragma unroll
        for (int it = 0; it < 16; it++) {
            size_t g = base + (size_t)it * stride;   // g = n*4096 + m
            int v = adj[g];
            unsigned long long m = __ballot(v != 0);
            if ((threadIdx.x & 63) == 0) {
                int n = (int)(g >> 12);
                int c = (int)((g >> 6) & 63);
                bitsT[(size_t)c * N_ + n] = m;
            }
        }
    } else if (b < 4096 + 1024) {
        // ---- split_x ----
        size_t g = ((size_t)(b - 4096) * 256 + threadIdx.x) * 8;
        float4 v0 = *(const float4*)(x + g);
        float4 v1 = *(const float4*)(x + g + 4);
        float v[8] = {v0.x, v0.y, v0.z, v0.w, v1.x, v1.y, v1.z, v1.w};
        uint32_t ph[4], pl[4];
#pragma unroll
        for (int i = 0; i < 4; i++) {
            float h0, h1, d0, d1;
            ph[i] = rne_pack2(v[2 * i], v[2 * i + 1], h0, h1);
            pl[i] = rne_pack2(v[2 * i] - h0, v[2 * i + 1] - h1, d0, d1);
        }
        *(uint4*)(xh + g) = make_uint4(ph[0], ph[1], ph[2], ph[3]);
        *(uint4*)(xl + g) = make_uint4(pl[0], pl[1], pl[2], pl[3]);
    } else {
        // ---- split_wT ----
        const int idx = b - 5120;
        const int kb = idx & 7;
        const int h  = idx >> 3;
        const int t  = threadIdx.x;
        {
            int kk = t >> 2, os = (t & 3) * 16;
            const float* src = W + ((size_t)h * IN_ + kb * 64 + kk) * OUT_ + os;
#pragma unroll
            for (int j = 0; j < 4; j++)
                *(float4*)&T[kk * 68 + os + j * 4] = *(const float4*)(src + j * 4);
        }
        __syncthreads();
        int o = t >> 2, ks = (t & 3) * 16;
        uint32_t ph[8], pl[8];
#pragma unroll
        for (int i = 0; i < 8; i++) {
            float va = T[(ks + 2 * i) * 68 + o], vb = T[(ks + 2 * i + 1) * 68 + o];
            float h0, h1, d0, d1;
            ph[i] = rne_pack2(va, vb, h0, h1);
            pl[i] = rne_pack2(va - h0, vb - h1, d0, d1);
        }
        size_t dst = ((size_t)h * OUT_ + o) * IN_ + kb * 64 + ks;
        *(uint4*)&WTh[dst]     = make_uint4(ph[0], ph[1], ph[2], ph[3]);
        *(uint4*)&WTh[dst + 8] = make_uint4(ph[4], ph[5], ph[6], ph[7]);
        *(uint4*)&WTl[dst]     = make_uint4(pl[0], pl[1], pl[2], pl[3]);
        *(uint4*)&WTl[dst + 8] = make_uint4(pl[4], pl[5], pl[6], pl[7]);
    }
}

// ---------- Wh = x@W via MFMA. FROZEN (R6 dbuf version, measured -7us on total).
__global__ __launch_bounds__(256) void wh_mfma(const uint16_t* __restrict__ xh,
                                               const uint16_t* __restrict__ xl,
                                               const uint16_t* __restrict__ WTh,
                                               const uint16_t* __restrict__ WTl,
                                               const float* __restrict__ a1,
                                               const float* __restrict__ a2,
                                               uint16_t* __restrict__ WhhT,
                                               float* __restrict__ f1,
                                               float* __restrict__ f2) {
    __shared__ __align__(16) char ldsbuf[2][4 * 64 * 72 * 2];   // 73728 B
    const int t  = threadIdx.x;
    const int h  = blockIdx.y;
    const int n0 = blockIdx.x * 64;
    const int l  = t & 63, w = t >> 6;
    const int p  = l & 15, q = l >> 4;
    const int sr = t >> 2, sc = (t & 3) * 16;

    f32x4 acc[4];
#pragma unroll
    for (int rt = 0; rt < 4; rt++) acc[rt] = (f32x4){0.f, 0.f, 0.f, 0.f};

    const uint16_t* gxh = xh + (size_t)(n0 + sr) * IN_ + sc;
    const uint16_t* gxl = xl + (size_t)(n0 + sr) * IN_ + sc;
    const uint16_t* gbh = WTh + ((size_t)h * OUT_ + sr) * IN_ + sc;
    const uint16_t* gbl = WTl + ((size_t)h * OUT_ + sr) * IN_ + sc;

    // prologue: stage kt=0 into buffer 0
    {
        uint4 a0 = *(const uint4*)(gxh);
        uint4 a1v = *(const uint4*)(gxh + 8);
        uint4 b0 = *(const uint4*)(gxl);
        uint4 b1 = *(const uint4*)(gxl + 8);
        uint4 c0 = *(const uint4*)(gbh);
        uint4 c1 = *(const uint4*)(gbh + 8);
        uint4 d0 = *(const uint4*)(gbl);
        uint4 d1 = *(const uint4*)(gbl + 8);
        uint16_t* Ah = (uint16_t*)ldsbuf[0];
        uint16_t* Al = Ah + 64 * 72;
        uint16_t* Bh = Al + 64 * 72;
        uint16_t* Bl = Bh + 64 * 72;
        *(uint4*)&Ah[sr * 72 + sc]     = a0;
        *(uint4*)&Ah[sr * 72 + sc + 8] = a1v;
        *(uint4*)&Al[sr * 72 + sc]     = b0;
        *(uint4*)&Al[sr * 72 + sc + 8] = b1;
        *(uint4*)&Bh[sr * 72 + sc]     = c0;
        *(uint4*)&Bh[sr * 72 + sc + 8] = c1;
        *(uint4*)&Bl[sr * 72 + sc]     = d0;
        *(uint4*)&Bl[sr * 72 + sc + 8] = d1;
    }

    for (int kt = 0; kt < 8; kt++) {
        __syncthreads();   // buf[kt&1] writes visible; buf[kt&1^1] reads (kt-1) done
        // prefetch kt+1 (last iter re-reads kt=0: dead values, always in-bounds)
        const int ktn = (kt + 1) & 7;
        uint4 a0 = *(const uint4*)(gxh + ktn * 64);
        uint4 a1v = *(const uint4*)(gxh + ktn * 64 + 8);
        uint4 b0 = *(const uint4*)(gxl + ktn * 64);
        uint4 b1 = *(const uint4*)(gxl + ktn * 64 + 8);
        uint4 c0 = *(const uint4*)(gbh + ktn * 64);
        uint4 c1 = *(const uint4*)(gbh + ktn * 64 + 8);
        uint4 d0 = *(const uint4*)(gbl + ktn * 64);
        uint4 d1 = *(const uint4*)(gbl + ktn * 64 + 8);

        const uint16_t* Ah = (const uint16_t*)ldsbuf[kt & 1];
        const uint16_t* Al = Ah + 64 * 72;
        const uint16_t* Bh = Al + 64 * 72;
        const uint16_t* Bl = Bh + 64 * 72;
#pragma unroll
        for (int k0 = 0; k0 < 2; k0++) {
            short8 bhf = *(const short8*)&Bh[(w * 16 + p) * 72 + q * 8 + k0 * 32];
            short8 blf = *(const short8*)&Bl[(w * 16 + p) * 72 + q * 8 + k0 * 32];
#pragma unroll
            for (int rt = 0; rt < 4; rt++) {
                short8 ahf = *(const short8*)&Ah[(rt * 16 + p) * 72 + q * 8 + k0 * 32];
                short8 alf = *(const short8*)&Al[(rt * 16 + p) * 72 + q * 8 + k0 * 32];
                acc[rt] = __builtin_amdgcn_mfma_f32_16x16x32_bf16(ahf, bhf, acc[rt], 0, 0, 0);
                acc[rt] = __builtin_amdgcn_mfma_f32_16x16x32_bf16(alf, bhf, acc[rt], 0, 0, 0);
                acc[rt] = __builtin_amdgcn_mfma_f32_16x16x32_bf16(ahf, blf, acc[rt], 0, 0, 0);
            }
        }
        // write-late: stage kt+1 into the other buffer
        uint16_t* nAh = (uint16_t*)ldsbuf[(kt & 1) ^ 1];
        uint16_t* nAl = nAh + 64 * 72;
        uint16_t* nBh = nAl + 64 * 72;
        uint16_t* nBl = nBh + 64 * 72;
        *(uint4*)&nAh[sr * 72 + sc]     = a0;
        *(uint4*)&nAh[sr * 72 + sc + 8] = a1v;
        *(uint4*)&nAl[sr * 72 + sc]     = b0;
        *(uint4*)&nAl[sr * 72 + sc + 8] = b1;
        *(uint4*)&nBh[sr * 72 + sc]     = c0;
        *(uint4*)&nBh[sr * 72 + sc + 8] = c1;
        *(uint4*)&nBl[sr * 72 + sc]     = d0;
        *(uint4*)&nBl[sr * 72 + sc + 8] = d1;
    }
    __syncthreads();
    float* Whs = (float*)ldsbuf[0];   // 64*68 floats = 17408 B
#pragma unroll
    for (int rt = 0; rt < 4; rt++)
#pragma unroll
        for (int reg = 0; reg < 4; reg++)
            Whs[(rt * 16 + q * 4 + reg) * 68 + w * 16 + p] = acc[rt][reg];
    __syncthreads();
    {   // f1/f2: thread group of 4 covers one row
        int r = t >> 2, og = (t & 3) * 16;
        float s1 = 0.f, s2 = 0.f;
#pragma unroll
        for (int j = 0; j < 4; j++) {
            float4 wv = *(const float4*)&Whs[r * 68 + og + j * 4];
            float4 av = *(const float4*)(a1 + h * OUT_ + og + j * 4);
            float4 bv = *(const float4*)(a2 + h * OUT_ + og + j * 4);
            s1 += wv.x * av.x + wv.y * av.y + wv.z * av.z + wv.w * av.w;
            s2 += wv.x * bv.x + wv.y * bv.y + wv.z * bv.z + wv.w * bv.w;
        }
        s1 += __shfl_xor(s1, 1, 64); s1 += __shfl_xor(s1, 2, 64);
        s2 += __shfl_xor(s2, 1, 64); s2 += __shfl_xor(s2, 2, 64);
        if ((t & 3) == 0) {
            f1[(size_t)h * N_ + n0 + r] = s1;
            f2[(size_t)h * N_ + n0 + r] = s2;
        }
    }
    {   // WhhT bf16 (hi only), [h][o][n]
        int o = t >> 2, ns = (t & 3) * 16;
        uint32_t ph[8];
#pragma unroll
        for (int i = 0; i < 8; i++) {
            float va = Whs[(ns + 2 * i) * 68 + o], vb = Whs[(ns + 2 * i + 1) * 68 + o];
            float h0, h1;
            ph[i] = rne_pack2(va, vb, h0, h1);
        }
        size_t dst = ((size_t)h * OUT_ + o) * N_ + n0 + ns;
        *(uint4*)&WhhT[dst]     = make_uint4(ph[0], ph[1], ph[2], ph[3]);
        *(uint4*)&WhhT[dst + 8] = make_uint4(ph[4], ph[5], ph[6], ph[7]);
    }
}

// ---------- main (fused z-halves): 512 threads = 2 groups of 4 waves.
// R9 (64.0 us proven) with ONE change: 4-buffer LDS ring, one barrier per
// 2-chunk window (16 barriers instead of 32). Window w reads bufs
// {2w&3,(2w+1)&3} and writes {(2w+2)&3,(2w+3)&3} -- disjoint; write->read and
// read->write orderings each cross a window barrier. LDB stays 72 (144B rows,
// 16B-aligned -> b128 preserved; R3's regression was LDB=76 alignment, not the
// ring). Per-chunk compute body + f2/bits depth-1 rotation byte-identical to
// R9 -> bit-exact. Tail over-reads stay inside d_ws (dead values).
__global__ __launch_bounds__(512, 4) void gat_main(const unsigned long long* __restrict__ bitsT,
                                                   const uint16_t* __restrict__ WhhT,
                                                   const float* __restrict__ f1,
                                                   const float* __restrict__ f2,
                                                   float* __restrict__ out) {
    __shared__ __align__(16) uint16_t Bh[2][4][64 * 72];   // 73728 B
    const int t   = threadIdx.x;
    const int h   = blockIdx.y;
    const int n0  = blockIdx.x * 64;
    const int grp = t >> 8;            // z-half (0: chunks 0..31, 1: 32..63)
    const int tg  = t & 255;           // thread-in-group
    const int l   = t & 63;
    const int wg  = tg >> 6;           // wave-in-group 0..3
    const int p   = l & 15, q = l >> 4;
    const int sr  = tg >> 2, sc = (tg & 3) * 16;
    const int row = wg * 16 + p;       // this lane's P row (A-frag m)

    const float f1v = f1[(size_t)h * N_ + n0 + row];
    const float* f2b = f2 + (size_t)h * N_ + (size_t)grp * 2048;
    const uint16_t* gb = WhhT + ((size_t)h * OUT_ + sr) * N_ + (size_t)grp * 2048 + sc;
    const unsigned long long* bp = bitsT + (size_t)(grp * 32) * N_ + n0 + row;

    float Lp = 0.f;
    f32x4 acc[4];
#pragma unroll
    for (int ct = 0; ct < 4; ct++) acc[ct] = (f32x4){0.f, 0.f, 0.f, 0.f};

    // prologue: stage chunks 0,1 into bufs 0,1; chunk-0 bits/f2 into regs
    {
        uint4 b0 = *(const uint4*)(gb);
        uint4 b1 = *(const uint4*)(gb + 8);
        uint4 c0 = *(const uint4*)(gb + 64);
        uint4 c1 = *(const uint4*)(gb + 64 + 8);
        *(uint4*)&Bh[grp][0][sr * 72 + sc]     = b0;
        *(uint4*)&Bh[grp][0][sr * 72 + sc + 8] = b1;
        *(uint4*)&Bh[grp][1][sr * 72 + sc]     = c0;
        *(uint4*)&Bh[grp][1][sr * 72 + sc + 8] = c1;
    }
    unsigned long long word = bp[0];
    bp += N_;
    float4 fa0, fa1, fb0, fb1;
    {
        const float* fpc = f2b + q * 8;
        fa0 = *(const float4*)(fpc);
        fa1 = *(const float4*)(fpc + 4);
        fb0 = *(const float4*)(fpc + 32);
        fb1 = *(const float4*)(fpc + 36);
    }

    for (int wdw = 0; wdw < 16; wdw++) {
        const int c0 = wdw * 2;
        __syncthreads();   // bufs c0&3,(c0+1)&3 filled; their writers past reads
        // issue global tile prefetches for chunks c0+2, c0+3 (stay in flight
        // across both chunks' compute; tail windows over-read into adjacent ws
        // regions -- in-bounds of d_ws, values dead)
        uint4 pa0 = *(const uint4*)(gb + (c0 + 2) * 64);
        uint4 pa1 = *(const uint4*)(gb + (c0 + 2) * 64 + 8);
        uint4 pb0 = *(const uint4*)(gb + (c0 + 3) * 64);
        uint4 pb1 = *(const uint4*)(gb + (c0 + 3) * 64 + 8);
#pragma unroll
        for (int sub = 0; sub < 2; sub++) {
            const int cc = c0 + sub;
            // depth-1 prefetch of next chunk's bits/f2 (registers, no hazards)
            unsigned long long nword = *bp;
            bp += N_;
            const float* fpn = f2b + (cc + 1) * 64 + q * 8;
            float4 fna0 = *(const float4*)(fpn);
            float4 fna1 = *(const float4*)(fpn + 4);
            float4 fnb0 = *(const float4*)(fpn + 32);
            float4 fnb1 = *(const float4*)(fpn + 36);
            const uint16_t* Bcur = &Bh[grp][cc & 3][0];
#pragma unroll
            for (int k0 = 0; k0 < 2; k0++) {
                float fs[8];
                if (k0 == 0) {
                    fs[0] = fa0.x; fs[1] = fa0.y; fs[2] = fa0.z; fs[3] = fa0.w;
                    fs[4] = fa1.x; fs[5] = fa1.y; fs[6] = fa1.z; fs[7] = fa1.w;
                } else {
                    fs[0] = fb0.x; fs[1] = fb0.y; fs[2] = fb0.z; fs[3] = fb0.w;
                    fs[4] = fb1.x; fs[5] = fb1.y; fs[6] = fb1.z; fs[7] = fb1.w;
                }
                uint32_t bits8 = (uint32_t)(word >> (k0 * 32 + q * 8)) & 0xffu;
                float pv[8];
#pragma unroll
                for (int j = 0; j < 8; j++) {
                    float s = f1v + fs[j];
                    float e = fmaxf(s, ALPHA_ * s);
                    float ex = __expf(e);
                    // mask via sign-extended bit: AND with 0 / ~0 is bit-exact
                    uint32_t msk = (uint32_t)((int32_t)(bits8 << (31 - j)) >> 31);
                    pv[j] = __uint_as_float(__float_as_uint(ex) & msk);
                }
                union { short8 s8; uint32_t u[4]; } af;
#pragma unroll
                for (int i = 0; i < 4; i++) {
                    uint32_t pk;
                    asm("v_cvt_pk_bf16_f32 %0, %1, %2"
                        : "=v"(pk) : "v"(pv[2 * i]), "v"(pv[2 * i + 1]));
                    af.u[i] = pk;
                    // denominator from the SAME rounded values, same add order
                    Lp += __uint_as_float(pk << 16) + __uint_as_float(pk & 0xffff0000u);
                }
#pragma unroll
                for (int ct = 0; ct < 4; ct++) {
                    short8 bhf = *(const short8*)&Bcur[(ct * 16 + p) * 72 + q * 8 + k0 * 32];
                    acc[ct] = __builtin_amdgcn_mfma_f32_16x16x32_bf16(af.s8, bhf, acc[ct], 0, 0, 0);
                }
            }
            word = nword;
            fa0 = fna0; fa1 = fna1; fb0 = fnb0; fb1 = fnb1;
        }
        // write-late: stage chunks c0+2, c0+3 into the two idle buffers
        uint16_t* Bw2 = &Bh[grp][(c0 + 2) & 3][0];
        uint16_t* Bw3 = &Bh[grp][(c0 + 3) & 3][0];
        *(uint4*)&Bw2[sr * 72 + sc]     = pa0;
        *(uint4*)&Bw2[sr * 72 + sc + 8] = pa1;
        *(uint4*)&Bw3[sr * 72 + sc]     = pb0;
        *(uint4*)&Bw3[sr * 72 + sc + 8] = pb1;
    }
    // reduce Lp across the 4 q-lanes sharing this row (same order as before)
    float Ls = Lp;
    Ls += __shfl_xor(Ls, 16, 64);
    Ls += __shfl_xor(Ls, 32, 64);

    // ---- cross-half reduction in LDS ----
    __syncthreads();                       // all loop LDS traffic done; reuse buffer
    float* Red  = (float*)&Bh[0][0][0];    // [2][64] row denominators
    float* Lsum = Red + 128;               // [64][68] group-1 numerators
    if (q == 0) Red[grp * 64 + row] = Ls;
    if (grp == 1) {
#pragma unroll
        for (int ct = 0; ct < 4; ct++)
#pragma unroll
            for (int reg = 0; reg < 4; reg++)
                Lsum[(wg * 16 + q * 4 + reg) * 68 + ct * 16 + p] = acc[ct][reg];
    }
    __syncthreads();
    if (grp == 0) {
        float inv[4];
#pragma unroll
        for (int reg = 0; reg < 4; reg++) {
            int rr = wg * 16 + q * 4 + reg;
            float L = Red[rr] + Red[64 + rr];   // L_z0 + L_z1, same order as combine
            inv[reg] = 1.f / L;
        }
#pragma unroll
        for (int ct = 0; ct < 4; ct++)
#pragma unroll
            for (int reg = 0; reg < 4; reg++) {
                int rr = wg * 16 + q * 4 + reg;
                float v = (acc[ct][reg] + Lsum[rr * 68 + ct * 16 + p]) * inv[reg];
                out[(size_t)(n0 + rr) * (H_ * OUT_) + h * OUT_ + ct * 16 + p] = v;
            }
    }
}

extern "C" void kernel_launch(void* const* d_in, const int* in_sizes, int n_in,
                              void* d_out, int out_size, void* d_ws, size_t ws_size,
                              hipStream_t stream) {
    const float* x   = nullptr;
    const int*   adj = nullptr;
    const float* W   = nullptr;
    const float* a1  = nullptr;
    const float* a2  = nullptr;
    for (int i = 0; i < n_in; i++) {
        long long sz = in_sizes[i];
        if      (sz == (long long)N_ * IN_)        x   = (const float*)d_in[i];
        else if (sz == (long long)N_ * N_)         adj = (const int*)d_in[i];
        else if (sz == (long long)H_ * IN_ * OUT_) W   = (const float*)d_in[i];
        else if (sz == (long long)H_ * OUT_) {
            if (!a1) a1 = (const float*)d_in[i];
            else     a2 = (const float*)d_in[i];
        }
    }
    if (!x)   x   = (const float*)d_in[0];
    if (!adj) adj = (const int*)d_in[1];
    if (!W)   W   = (const float*)d_in[2];
    if (!a1)  a1  = (const float*)d_in[3];
    if (!a2)  a2  = (const float*)d_in[4];
    float* out = (float*)d_out;

    char* ws = (char*)d_ws;
    unsigned long long* bitsT = (unsigned long long*)ws;                     // 2 MB @0
    uint16_t* WhhT = (uint16_t*)(ws + (2u  << 20));                          // 4 MB @2M
    float* f1      = (float*)   (ws + (6u  << 20));                          // 128 KB
    float* f2      = (float*)   (ws + (6u  << 20) + (128u << 10));           // 128 KB
    uint16_t* xh   = (uint16_t*)(ws + (6u  << 20) + (512u << 10));           // 4 MB (phase 1)
    uint16_t* xl   = (uint16_t*)(ws + (10u << 20) + (512u << 10));           // 4 MB (phase 1)
    uint16_t* WTh  = (uint16_t*)(ws + (14u << 20) + (512u << 10));           // 512 KB (phase 1)
    uint16_t* WTl  = (uint16_t*)(ws + (15u << 20));                          // 512 KB (phase 1)

    preprocess<<<4096 + 1024 + 64, 256, 0, stream>>>(adj, bitsT, x, xh, xl, W, WTh, WTl);
    wh_mfma<<<dim3(N_ / 64, H_), 256, 0, stream>>>(xh, xl, WTh, WTl, a1, a2, WhhT, f1, f2);
    gat_main<<<dim3(N_ / 64, H_), 512, 0, stream>>>(bitsT, WhhT, f1, f2, out);
}

// Round 11
// 178.746 us; speedup vs baseline: 1.0299x; 1.0299x over previous
//
#include <hip/hip_runtime.h>
#include <hip/hip_bf16.h>
#include <stdint.h>

// N=4096, IN=512, OUT=64, H=8. Inputs (fp32): x, adj(int32), W, a1, a2. Output fp32[N, H*OUT].
// ws: bitsT 2MB @0 | WhhT 4MB @2M | f1 @6M | f2 @6M+128K |
//     xh 4MB @6.5M | xl 4MB @10.5M | WTh 512K @14.5M | WTl 512K @15M

constexpr int N_ = 4096, IN_ = 512, OUT_ = 64, H_ = 8;
constexpr float ALPHA_ = 0.2f;

typedef __attribute__((ext_vector_type(8))) short short8;
typedef __attribute__((ext_vector_type(4))) float f32x4;

__device__ __forceinline__ uint32_t rne_pack2(float a, float b, float& ra, float& rb) {
    uint32_t ua = __float_as_uint(a); ua += 0x7fffu + ((ua >> 16) & 1u); ua >>= 16;
    uint32_t ub = __float_as_uint(b); ub += 0x7fffu + ((ub >> 16) & 1u); ub >>= 16;
    ra = __uint_as_float(ua << 16);
    rb = __uint_as_float(ub << 16);
    return ua | (ub << 16);
}

// ---------- fused preprocessing: pack_adj (blocks 0..4095) | split_x (4096..5119)
// | split_wT (5120..5183). FROZEN (R6).
__global__ __launch_bounds__(256) void preprocess(const int* __restrict__ adj,
                                                  unsigned long long* __restrict__ bitsT,
                                                  const float* __restrict__ x,
                                                  uint16_t* __restrict__ xh,
                                                  uint16_t* __restrict__ xl,
                                                  const float* __restrict__ W,
                                                  uint16_t* __restrict__ WTh,
                                                  uint16_t* __restrict__ WTl) {
    __shared__ float T[64 * 68];
    const int b = blockIdx.x;
    if (b < 4096) {
        // ---- pack_adj ----
        size_t base = (size_t)b * 256 + threadIdx.x;
        const size_t stride = (size_t)4096 * 256;
#pragma unroll
        for (int it = 0; it < 16; it++) {
            size_t g = base + (size_t)it * stride;   // g = n*4096 + m
            int v = adj[g];
            unsigned long long m = __ballot(v != 0);
            if ((threadIdx.x & 63) == 0) {
                int n = (int)(g >> 12);
                int c = (int)((g >> 6) & 63);
                bitsT[(size_t)c * N_ + n] = m;
            }
        }
    } else if (b < 4096 + 1024) {
        // ---- split_x ----
        size_t g = ((size_t)(b - 4096) * 256 + threadIdx.x) * 8;
        float4 v0 = *(const float4*)(x + g);
        float4 v1 = *(const float4*)(x + g + 4);
        float v[8] = {v0.x, v0.y, v0.z, v0.w, v1.x, v1.y, v1.z, v1.w};
        uint32_t ph[4], pl[4];
#pragma unroll
        for (int i = 0; i < 4; i++) {
            float h0, h1, d0, d1;
            ph[i] = rne_pack2(v[2 * i], v[2 * i + 1], h0, h1);
            pl[i] = rne_pack2(v[2 * i] - h0, v[2 * i + 1] - h1, d0, d1);
        }
        *(uint4*)(xh + g) = make_uint4(ph[0], ph[1], ph[2], ph[3]);
        *(uint4*)(xl + g) = make_uint4(pl[0], pl[1], pl[2], pl[3]);
    } else {
        // ---- split_wT ----
        const int idx = b - 5120;
        const int kb = idx & 7;
        const int h  = idx >> 3;
        const int t  = threadIdx.x;
        {
            int kk = t >> 2, os = (t & 3) * 16;
            const float* src = W + ((size_t)h * IN_ + kb * 64 + kk) * OUT_ + os;
#pragma unroll
            for (int j = 0; j < 4; j++)
                *(float4*)&T[kk * 68 + os + j * 4] = *(const float4*)(src + j * 4);
        }
        __syncthreads();
        int o = t >> 2, ks = (t & 3) * 16;
        uint32_t ph[8], pl[8];
#pragma unroll
        for (int i = 0; i < 8; i++) {
            float va = T[(ks + 2 * i) * 68 + o], vb = T[(ks + 2 * i + 1) * 68 + o];
            float h0, h1, d0, d1;
            ph[i] = rne_pack2(va, vb, h0, h1);
            pl[i] = rne_pack2(va - h0, vb - h1, d0, d1);
        }
        size_t dst = ((size_t)h * OUT_ + o) * IN_ + kb * 64 + ks;
        *(uint4*)&WTh[dst]     = make_uint4(ph[0], ph[1], ph[2], ph[3]);
        *(uint4*)&WTh[dst + 8] = make_uint4(ph[4], ph[5], ph[6], ph[7]);
        *(uint4*)&WTl[dst]     = make_uint4(pl[0], pl[1], pl[2], pl[3]);
        *(uint4*)&WTl[dst + 8] = make_uint4(pl[4], pl[5], pl[6], pl[7]);
    }
}

// ---------- Wh = x@W via MFMA. FROZEN (R6 dbuf version, measured -7us on total).
__global__ __launch_bounds__(256) void wh_mfma(const uint16_t* __restrict__ xh,
                                               const uint16_t* __restrict__ xl,
                                               const uint16_t* __restrict__ WTh,
                                               const uint16_t* __restrict__ WTl,
                                               const float* __restrict__ a1,
                                               const float* __restrict__ a2,
                                               uint16_t* __restrict__ WhhT,
                                               float* __restrict__ f1,
                                               float* __restrict__ f2) {
    __shared__ __align__(16) char ldsbuf[2][4 * 64 * 72 * 2];   // 73728 B
    const int t  = threadIdx.x;
    const int h  = blockIdx.y;
    const int n0 = blockIdx.x * 64;
    const int l  = t & 63, w = t >> 6;
    const int p  = l & 15, q = l >> 4;
    const int sr = t >> 2, sc = (t & 3) * 16;

    f32x4 acc[4];
#pragma unroll
    for (int rt = 0; rt < 4; rt++) acc[rt] = (f32x4){0.f, 0.f, 0.f, 0.f};

    const uint16_t* gxh = xh + (size_t)(n0 + sr) * IN_ + sc;
    const uint16_t* gxl = xl + (size_t)(n0 + sr) * IN_ + sc;
    const uint16_t* gbh = WTh + ((size_t)h * OUT_ + sr) * IN_ + sc;
    const uint16_t* gbl = WTl + ((size_t)h * OUT_ + sr) * IN_ + sc;

    // prologue: stage kt=0 into buffer 0
    {
        uint4 a0 = *(const uint4*)(gxh);
        uint4 a1v = *(const uint4*)(gxh + 8);
        uint4 b0 = *(const uint4*)(gxl);
        uint4 b1 = *(const uint4*)(gxl + 8);
        uint4 c0 = *(const uint4*)(gbh);
        uint4 c1 = *(const uint4*)(gbh + 8);
        uint4 d0 = *(const uint4*)(gbl);
        uint4 d1 = *(const uint4*)(gbl + 8);
        uint16_t* Ah = (uint16_t*)ldsbuf[0];
        uint16_t* Al = Ah + 64 * 72;
        uint16_t* Bh = Al + 64 * 72;
        uint16_t* Bl = Bh + 64 * 72;
        *(uint4*)&Ah[sr * 72 + sc]     = a0;
        *(uint4*)&Ah[sr * 72 + sc + 8] = a1v;
        *(uint4*)&Al[sr * 72 + sc]     = b0;
        *(uint4*)&Al[sr * 72 + sc + 8] = b1;
        *(uint4*)&Bh[sr * 72 + sc]     = c0;
        *(uint4*)&Bh[sr * 72 + sc + 8] = c1;
        *(uint4*)&Bl[sr * 72 + sc]     = d0;
        *(uint4*)&Bl[sr * 72 + sc + 8] = d1;
    }

    for (int kt = 0; kt < 8; kt++) {
        __syncthreads();   // buf[kt&1] writes visible; buf[kt&1^1] reads (kt-1) done
        // prefetch kt+1 (last iter re-reads kt=0: dead values, always in-bounds)
        const int ktn = (kt + 1) & 7;
        uint4 a0 = *(const uint4*)(gxh + ktn * 64);
        uint4 a1v = *(const uint4*)(gxh + ktn * 64 + 8);
        uint4 b0 = *(const uint4*)(gxl + ktn * 64);
        uint4 b1 = *(const uint4*)(gxl + ktn * 64 + 8);
        uint4 c0 = *(const uint4*)(gbh + ktn * 64);
        uint4 c1 = *(const uint4*)(gbh + ktn * 64 + 8);
        uint4 d0 = *(const uint4*)(gbl + ktn * 64);
        uint4 d1 = *(const uint4*)(gbl + ktn * 64 + 8);

        const uint16_t* Ah = (const uint16_t*)ldsbuf[kt & 1];
        const uint16_t* Al = Ah + 64 * 72;
        const uint16_t* Bh = Al + 64 * 72;
        const uint16_t* Bl = Bh + 64 * 72;
#pragma unroll
        for (int k0 = 0; k0 < 2; k0++) {
            short8 bhf = *(const short8*)&Bh[(w * 16 + p) * 72 + q * 8 + k0 * 32];
            short8 blf = *(const short8*)&Bl[(w * 16 + p) * 72 + q * 8 + k0 * 32];
#pragma unroll
            for (int rt = 0; rt < 4; rt++) {
                short8 ahf = *(const short8*)&Ah[(rt * 16 + p) * 72 + q * 8 + k0 * 32];
                short8 alf = *(const short8*)&Al[(rt * 16 + p) * 72 + q * 8 + k0 * 32];
                acc[rt] = __builtin_amdgcn_mfma_f32_16x16x32_bf16(ahf, bhf, acc[rt], 0, 0, 0);
                acc[rt] = __builtin_amdgcn_mfma_f32_16x16x32_bf16(alf, bhf, acc[rt], 0, 0, 0);
                acc[rt] = __builtin_amdgcn_mfma_f32_16x16x32_bf16(ahf, blf, acc[rt], 0, 0, 0);
            }
        }
        // write-late: stage kt+1 into the other buffer
        uint16_t* nAh = (uint16_t*)ldsbuf[(kt & 1) ^ 1];
        uint16_t* nAl = nAh + 64 * 72;
        uint16_t* nBh = nAl + 64 * 72;
        uint16_t* nBl = nBh + 64 * 72;
        *(uint4*)&nAh[sr * 72 + sc]     = a0;
        *(uint4*)&nAh[sr * 72 + sc + 8] = a1v;
        *(uint4*)&nAl[sr * 72 + sc]     = b0;
        *(uint4*)&nAl[sr * 72 + sc + 8] = b1;
        *(uint4*)&nBh[sr * 72 + sc]     = c0;
        *(uint4*)&nBh[sr * 72 + sc + 8] = c1;
        *(uint4*)&nBl[sr * 72 + sc]     = d0;
        *(uint4*)&nBl[sr * 72 + sc + 8] = d1;
    }
    __syncthreads();
    float* Whs = (float*)ldsbuf[0];   // 64*68 floats = 17408 B
#pragma unroll
    for (int rt = 0; rt < 4; rt++)
#pragma unroll
        for (int reg = 0; reg < 4; reg++)
            Whs[(rt * 16 + q * 4 + reg) * 68 + w * 16 + p] = acc[rt][reg];
    __syncthreads();
    {   // f1/f2: thread group of 4 covers one row
        int r = t >> 2, og = (t & 3) * 16;
        float s1 = 0.f, s2 = 0.f;
#pragma unroll
        for (int j = 0; j < 4; j++) {
            float4 wv = *(const float4*)&Whs[r * 68 + og + j * 4];
            float4 av = *(const float4*)(a1 + h * OUT_ + og + j * 4);
            float4 bv = *(const float4*)(a2 + h * OUT_ + og + j * 4);
            s1 += wv.x * av.x + wv.y * av.y + wv.z * av.z + wv.w * av.w;
            s2 += wv.x * bv.x + wv.y * bv.y + wv.z * bv.z + wv.w * bv.w;
        }
        s1 += __shfl_xor(s1, 1, 64); s1 += __shfl_xor(s1, 2, 64);
        s2 += __shfl_xor(s2, 1, 64); s2 += __shfl_xor(s2, 2, 64);
        if ((t & 3) == 0) {
            f1[(size_t)h * N_ + n0 + r] = s1;
            f2[(size_t)h * N_ + n0 + r] = s2;
        }
    }
    {   // WhhT bf16 (hi only), [h][o][n]
        int o = t >> 2, ns = (t & 3) * 16;
        uint32_t ph[8];
#pragma unroll
        for (int i = 0; i < 8; i++) {
            float va = Whs[(ns + 2 * i) * 68 + o], vb = Whs[(ns + 2 * i + 1) * 68 + o];
            float h0, h1;
            ph[i] = rne_pack2(va, vb, h0, h1);
        }
        size_t dst = ((size_t)h * OUT_ + o) * N_ + n0 + ns;
        *(uint4*)&WhhT[dst]     = make_uint4(ph[0], ph[1], ph[2], ph[3]);
        *(uint4*)&WhhT[dst + 8] = make_uint4(ph[4], ph[5], ph[6], ph[7]);
    }
}

// ---------- main (fused z-halves): 512 threads = 2 groups of 4 waves.
// R10 (62.7 us proven: 4-buffer ring, 1 barrier / 2 chunks, f2/bits depth-1
// register prefetch) with ONE change: mask via 1-op __builtin_amdgcn_sbfe
// (builtin, scheduler-free) instead of the 2-op shl+ashr pair. sbfe sign-
// extends bit j to 0/~0 -- identical select, proven bit-exact in R3/R7 runs.
// Everything else byte-identical to R10.
__global__ __launch_bounds__(512, 4) void gat_main(const unsigned long long* __restrict__ bitsT,
                                                   const uint16_t* __restrict__ WhhT,
                                                   const float* __restrict__ f1,
                                                   const float* __restrict__ f2,
                                                   float* __restrict__ out) {
    __shared__ __align__(16) uint16_t Bh[2][4][64 * 72];   // 73728 B
    const int t   = threadIdx.x;
    const int h   = blockIdx.y;
    const int n0  = blockIdx.x * 64;
    const int grp = t >> 8;            // z-half (0: chunks 0..31, 1: 32..63)
    const int tg  = t & 255;           // thread-in-group
    const int l   = t & 63;
    const int wg  = tg >> 6;           // wave-in-group 0..3
    const int p   = l & 15, q = l >> 4;
    const int sr  = tg >> 2, sc = (tg & 3) * 16;
    const int row = wg * 16 + p;       // this lane's P row (A-frag m)

    const float f1v = f1[(size_t)h * N_ + n0 + row];
    const float* f2b = f2 + (size_t)h * N_ + (size_t)grp * 2048;
    const uint16_t* gb = WhhT + ((size_t)h * OUT_ + sr) * N_ + (size_t)grp * 2048 + sc;
    const unsigned long long* bp = bitsT + (size_t)(grp * 32) * N_ + n0 + row;

    float Lp = 0.f;
    f32x4 acc[4];
#pragma unroll
    for (int ct = 0; ct < 4; ct++) acc[ct] = (f32x4){0.f, 0.f, 0.f, 0.f};

    // prologue: stage chunks 0,1 into bufs 0,1; chunk-0 bits/f2 into regs
    {
        uint4 b0 = *(const uint4*)(gb);
        uint4 b1 = *(const uint4*)(gb + 8);
        uint4 c0 = *(const uint4*)(gb + 64);
        uint4 c1 = *(const uint4*)(gb + 64 + 8);
        *(uint4*)&Bh[grp][0][sr * 72 + sc]     = b0;
        *(uint4*)&Bh[grp][0][sr * 72 + sc + 8] = b1;
        *(uint4*)&Bh[grp][1][sr * 72 + sc]     = c0;
        *(uint4*)&Bh[grp][1][sr * 72 + sc + 8] = c1;
    }
    unsigned long long word = bp[0];
    bp += N_;
    float4 fa0, fa1, fb0, fb1;
    {
        const float* fpc = f2b + q * 8;
        fa0 = *(const float4*)(fpc);
        fa1 = *(const float4*)(fpc + 4);
        fb0 = *(const float4*)(fpc + 32);
        fb1 = *(const float4*)(fpc + 36);
    }

    for (int wdw = 0; wdw < 16; wdw++) {
        const int c0 = wdw * 2;
        __syncthreads();   // bufs c0&3,(c0+1)&3 filled; their writers past reads
        // issue global tile prefetches for chunks c0+2, c0+3 (stay in flight
        // across both chunks' compute; tail windows over-read into adjacent ws
        // regions -- in-bounds of d_ws, values dead)
        uint4 pa0 = *(const uint4*)(gb + (c0 + 2) * 64);
        uint4 pa1 = *(const uint4*)(gb + (c0 + 2) * 64 + 8);
        uint4 pb0 = *(const uint4*)(gb + (c0 + 3) * 64);
        uint4 pb1 = *(const uint4*)(gb + (c0 + 3) * 64 + 8);
#pragma unroll
        for (int sub = 0; sub < 2; sub++) {
            const int cc = c0 + sub;
            // depth-1 prefetch of next chunk's bits/f2 (registers, no hazards)
            unsigned long long nword = *bp;
            bp += N_;
            const float* fpn = f2b + (cc + 1) * 64 + q * 8;
            float4 fna0 = *(const float4*)(fpn);
            float4 fna1 = *(const float4*)(fpn + 4);
            float4 fnb0 = *(const float4*)(fpn + 32);
            float4 fnb1 = *(const float4*)(fpn + 36);
            const uint16_t* Bcur = &Bh[grp][cc & 3][0];
#pragma unroll
            for (int k0 = 0; k0 < 2; k0++) {
                float fs[8];
                if (k0 == 0) {
                    fs[0] = fa0.x; fs[1] = fa0.y; fs[2] = fa0.z; fs[3] = fa0.w;
                    fs[4] = fa1.x; fs[5] = fa1.y; fs[6] = fa1.z; fs[7] = fa1.w;
                } else {
                    fs[0] = fb0.x; fs[1] = fb0.y; fs[2] = fb0.z; fs[3] = fb0.w;
                    fs[4] = fb1.x; fs[5] = fb1.y; fs[6] = fb1.z; fs[7] = fb1.w;
                }
                uint32_t bits8 = (uint32_t)(word >> (k0 * 32 + q * 8)) & 0xffu;
                float pv[8];
#pragma unroll
                for (int j = 0; j < 8; j++) {
                    float s = f1v + fs[j];
                    float e = fmaxf(s, ALPHA_ * s);
                    float ex = __expf(e);
                    // mask via 1-op sign-extended bitfield extract (0 or ~0);
                    // AND select is bit-exact (proven R3/R7)
                    uint32_t msk = (uint32_t)__builtin_amdgcn_sbfe((int)bits8, j, 1);
                    pv[j] = __uint_as_float(__float_as_uint(ex) & msk);
                }
                union { short8 s8; uint32_t u[4]; } af;
#pragma unroll
                for (int i = 0; i < 4; i++) {
                    uint32_t pk;
                    asm("v_cvt_pk_bf16_f32 %0, %1, %2"
                        : "=v"(pk) : "v"(pv[2 * i]), "v"(pv[2 * i + 1]));
                    af.u[i] = pk;
                    // denominator from the SAME rounded values, same add order
                    Lp += __uint_as_float(pk << 16) + __uint_as_float(pk & 0xffff0000u);
                }
#pragma unroll
                for (int ct = 0; ct < 4; ct++) {
                    short8 bhf = *(const short8*)&Bcur[(ct * 16 + p) * 72 + q * 8 + k0 * 32];
                    acc[ct] = __builtin_amdgcn_mfma_f32_16x16x32_bf16(af.s8, bhf, acc[ct], 0, 0, 0);
                }
            }
            word = nword;
            fa0 = fna0; fa1 = fna1; fb0 = fnb0; fb1 = fnb1;
        }
        // write-late: stage chunks c0+2, c0+3 into the two idle buffers
        uint16_t* Bw2 = &Bh[grp][(c0 + 2) & 3][0];
        uint16_t* Bw3 = &Bh[grp][(c0 + 3) & 3][0];
        *(uint4*)&Bw2[sr * 72 + sc]     = pa0;
        *(uint4*)&Bw2[sr * 72 + sc + 8] = pa1;
        *(uint4*)&Bw3[sr * 72 + sc]     = pb0;
        *(uint4*)&Bw3[sr * 72 + sc + 8] = pb1;
    }
    // reduce Lp across the 4 q-lanes sharing this row (same order as before)
    float Ls = Lp;
    Ls += __shfl_xor(Ls, 16, 64);
    Ls += __shfl_xor(Ls, 32, 64);

    // ---- cross-half reduction in LDS ----
    __syncthreads();                       // all loop LDS traffic done; reuse buffer
    float* Red  = (float*)&Bh[0][0][0];    // [2][64] row denominators
    float* Lsum = Red + 128;               // [64][68] group-1 numerators
    if (q == 0) Red[grp * 64 + row] = Ls;
    if (grp == 1) {
#pragma unroll
        for (int ct = 0; ct < 4; ct++)
#pragma unroll
            for (int reg = 0; reg < 4; reg++)
                Lsum[(wg * 16 + q * 4 + reg) * 68 + ct * 16 + p] = acc[ct][reg];
    }
    __syncthreads();
    if (grp == 0) {
        float inv[4];
#pragma unroll
        for (int reg = 0; reg < 4; reg++) {
            int rr = wg * 16 + q * 4 + reg;
            float L = Red[rr] + Red[64 + rr];   // L_z0 + L_z1, same order as combine
            inv[reg] = 1.f / L;
        }
#pragma unroll
        for (int ct = 0; ct < 4; ct++)
#pragma unroll
            for (int reg = 0; reg < 4; reg++) {
                int rr = wg * 16 + q * 4 + reg;
                float v = (acc[ct][reg] + Lsum[rr * 68 + ct * 16 + p]) * inv[reg];
                out[(size_t)(n0 + rr) * (H_ * OUT_) + h * OUT_ + ct * 16 + p] = v;
            }
    }
}

extern "C" void kernel_launch(void* const* d_in, const int* in_sizes, int n_in,
                              void* d_out, int out_size, void* d_ws, size_t ws_size,
                              hipStream_t stream) {
    const float* x   = nullptr;
    const int*   adj = nullptr;
    const float* W   = nullptr;
    const float* a1  = nullptr;
    const float* a2  = nullptr;
    for (int i = 0; i < n_in; i++) {
        long long sz = in_sizes[i];
        if      (sz == (long long)N_ * IN_)        x   = (const float*)d_in[i];
        else if (sz == (long long)N_ * N_)         adj = (const int*)d_in[i];
        else if (sz == (long long)H_ * IN_ * OUT_) W   = (const float*)d_in[i];
        else if (sz == (long long)H_ * OUT_) {
            if (!a1) a1 = (const float*)d_in[i];
            else     a2 = (const float*)d_in[i];
        }
    }
    if (!x)   x   = (const float*)d_in[0];
    if (!adj) adj = (const int*)d_in[1];
    if (!W)   W   = (const float*)d_in[2];
    if (!a1)  a1  = (const float*)d_in[3];
    if (!a2)  a2  = (const float*)d_in[4];
    float* out = (float*)d_out;

    char* ws = (char*)d_ws;
    unsigned long long* bitsT = (unsigned long long*)ws;                     // 2 MB @0
    uint16_t* WhhT = (uint16_t*)(ws + (2u  << 20));                          // 4 MB @2M
    float* f1      = (float*)   (ws + (6u  << 20));                          // 128 KB
    float* f2      = (float*)   (ws + (6u  << 20) + (128u << 10));           // 128 KB
    uint16_t* xh   = (uint16_t*)(ws + (6u  << 20) + (512u << 10));           // 4 MB (phase 1)
    uint16_t* xl   = (uint16_t*)(ws + (10u << 20) + (512u << 10));           // 4 MB (phase 1)
    uint16_t* WTh  = (uint16_t*)(ws + (14u << 20) + (512u << 10));           // 512 KB (phase 1)
    uint16_t* WTl  = (uint16_t*)(ws + (15u << 20));                          // 512 KB (phase 1)

    preprocess<<<4096 + 1024 + 64, 256, 0, stream>>>(adj, bitsT, x, xh, xl, W, WTh, WTl);
    wh_mfma<<<dim3(N_ / 64, H_), 256, 0, stream>>>(xh, xl, WTh, WTl, a1, a2, WhhT, f1, f2);
    gat_main<<<dim3(N_ / 64, H_), 512, 0, stream>>>(bitsT, WhhT, f1, f2, out);
}